// Round 1
// baseline (419.527 us; speedup 1.0000x reference)
//
#include <hip/hip_runtime.h>
#include <math.h>

#define NN 8192
#define MM 64
#define BB 128
#define HIDC 512
#define OUTC 256
#define SEQW 63

// ---- workspace layout (float offsets) ----
#define OFF_KR   0                       // B*64
#define OFF_KW   8192                    // B*64
#define OFF_PR   16384                   // B*8: beta,g,s0,s1,s2,gamma,knorm
#define OFF_PW   17408                   // B*8
#define OFF_BS   18432                   // B*8: wrp_sum, wwp_sum, dd2, dkr, swr
#define OFF_MSUM 19456                   // B*64  (zeroed each launch)
#define OFF_OUT0 27648                   // B*64  (zeroed each launch)
#define OFF_D    35840                   // B*64
#define OFF_DOTW 44032                   // B*N
#define OFF_DOTR (44032 + 1048576)       // B*N
#define OFF_RN2  (44032 + 2*1048576)     // B*N
#define OFF_DOTD (44032 + 3*1048576)     // B*N
#define OFF_WW   (44032 + 4*1048576)     // B*N
#define OFF_WR   (44032 + 5*1048576)     // B*N
// total = 6,335,488 floats = 25.4 MB

__device__ __forceinline__ float lrelu(float x){ return x > 0.f ? x : 0.01f*x; }
__device__ __forceinline__ float sigm(float x){ return 1.f/(1.f+expf(-x)); }

__device__ float block_reduce_sum(float v, float* red) {
  for (int m = 32; m >= 1; m >>= 1) v += __shfl_xor(v, m);
  int wid = threadIdx.x >> 6;
  int nw = (blockDim.x + 63) >> 6;
  if ((threadIdx.x & 63) == 0) red[wid] = v;
  __syncthreads();
  if (threadIdx.x == 0) { float s = 0.f; for (int i = 0; i < nw; ++i) s += red[i]; red[0] = s; }
  __syncthreads();
  float r = red[0];
  __syncthreads();
  return r;
}

__device__ float block_reduce_max(float v, float* red) {
  for (int m = 32; m >= 1; m >>= 1) v = fmaxf(v, __shfl_xor(v, m));
  int wid = threadIdx.x >> 6;
  int nw = (blockDim.x + 63) >> 6;
  if ((threadIdx.x & 63) == 0) red[wid] = v;
  __syncthreads();
  if (threadIdx.x == 0) { float s = red[0]; for (int i = 1; i < nw; ++i) s = fmaxf(s, red[i]); red[0] = s; }
  __syncthreads();
  float r = red[0];
  __syncthreads();
  return r;
}

// ---------------- controller MLP (tiny) ----------------
__global__ __launch_bounds__(512) void ctrl_kernel(
    const float* __restrict__ x,
    const float* __restrict__ W0, const float* __restrict__ b0,
    const float* __restrict__ W1, const float* __restrict__ b1,
    const float* __restrict__ Wc, const float* __restrict__ bc,
    const float* __restrict__ Wr, const float* __restrict__ br,
    const float* __restrict__ Ww, const float* __restrict__ bw,
    float* __restrict__ ws)
{
  int b = blockIdx.x, t = threadIdx.x;
  __shared__ float xs[64];
  __shared__ float h0[512];
  __shared__ float h1[512];
  __shared__ float ct[256];
  __shared__ float rr[70], rw[70];
  if (t < 64) xs[t] = x[b*64 + t];
  __syncthreads();
  float acc = b0[t];
  for (int i = 0; i < 64; ++i) acc += xs[i] * W0[i*HIDC + t];
  h0[t] = lrelu(acc);
  __syncthreads();
  acc = b1[t];
  for (int i = 0; i < 512; ++i) acc += h0[i] * W1[i*HIDC + t];
  h1[t] = lrelu(acc);
  __syncthreads();
  if (t < 256) {
    acc = bc[t];
    for (int i = 0; i < 512; ++i) acc += h1[i] * Wc[i*OUTC + t];
    ct[t] = lrelu(acc);
  }
  __syncthreads();
  if (t < 70) {
    float ar = br[t], aw = bw[t];
    for (int i = 0; i < 256; ++i) { float c = ct[i]; ar += c * Wr[i*70 + t]; aw += c * Ww[i*70 + t]; }
    rr[t] = ar; rw[t] = aw;
  }
  __syncthreads();
  if (t < 64) { ws[OFF_KR + b*64 + t] = rr[t]; ws[OFF_KW + b*64 + t] = rw[t]; }
  if (t == 0) {
    float* p = ws + OFF_PR + b*8;
    p[0] = fmaxf(rr[64], 0.f) + 1e-8f;
    p[1] = sigm(rr[65]);
    float m = fmaxf(rr[66], fmaxf(rr[67], rr[68]));
    float e0 = expf(rr[66]-m), e1 = expf(rr[67]-m), e2 = expf(rr[68]-m);
    float ss = e0+e1+e2;
    p[2] = e0/ss; p[3] = e1/ss; p[4] = e2/ss;
    p[5] = fmaxf(rr[69], 0.f) + 1.f;
    float n2 = 0.f; for (int i = 0; i < 64; ++i) n2 += rr[i]*rr[i];
    p[6] = sqrtf(n2);
  }
  if (t == 1) {
    float* p = ws + OFF_PW + b*8;
    p[0] = fmaxf(rw[64], 0.f) + 1e-8f;
    p[1] = sigm(rw[65]);
    float m = fmaxf(rw[66], fmaxf(rw[67], rw[68]));
    float e0 = expf(rw[66]-m), e1 = expf(rw[67]-m), e2 = expf(rw[68]-m);
    float ss = e0+e1+e2;
    p[2] = e0/ss; p[3] = e1/ss; p[4] = e2/ss;
    p[5] = fmaxf(rw[69], 0.f) + 1.f;
    float n2 = 0.f; for (int i = 0; i < 64; ++i) n2 += rw[i]*rw[i];
    p[6] = sqrtf(n2);
  }
}

// ---------------- w_prev sums ----------------
__global__ __launch_bounds__(256) void prevsum_kernel(
    const float* __restrict__ wrp, const float* __restrict__ wwp, float* __restrict__ ws)
{
  int b = blockIdx.x, t = threadIdx.x;
  __shared__ float red[16];
  float s0 = 0.f, s1 = 0.f;
  for (int n = t; n < NN; n += 256) {
    s0 += wrp[(size_t)b*NN + n];
    s1 += wwp[(size_t)b*NN + n];
  }
  float r0 = block_reduce_sum(s0, red);
  float r1 = block_reduce_sum(s1, red);
  if (t == 0) { ws[OFF_BS + b*8 + 0] = r0; ws[OFF_BS + b*8 + 1] = r1; }
}

// ---------------- bank pass 1: mem_sum, bank·kw, bank·kr, ||row||^2 ----------------
__global__ __launch_bounds__(256) void bank_pass1(const float* __restrict__ bank, float* __restrict__ ws)
{
  int blk = blockIdx.x;
  int b  = blk >> 7;              // N/64 = 128 chunks per batch
  int n0 = (blk & 127) << 6;      // 64 rows per block
  int t = threadIdx.x;
  int cg = t & 15;                // 16 lanes per row (4 floats each)
  int rl = t >> 4;                // 0..15
  __shared__ float kwS[64], krS[64], msum[64];
  if (t < 64) { kwS[t] = ws[OFF_KW + b*64 + t]; krS[t] = ws[OFF_KR + b*64 + t]; msum[t] = 0.f; }
  __syncthreads();
  float4 kw4 = *(float4*)&kwS[cg*4];
  float4 kr4 = *(float4*)&krS[cg*4];
  float m0=0.f, m1=0.f, m2=0.f, m3=0.f;
  for (int it = 0; it < 4; ++it) {
    int n = n0 + rl + it*16;
    const float4 v = *(const float4*)&bank[((size_t)b*NN + n)*MM + cg*4];
    float dw = v.x*kw4.x + v.y*kw4.y + v.z*kw4.z + v.w*kw4.w;
    float dr = v.x*kr4.x + v.y*kr4.y + v.z*kr4.z + v.w*kr4.w;
    float r2 = v.x*v.x + v.y*v.y + v.z*v.z + v.w*v.w;
    for (int m = 1; m < 16; m <<= 1) {
      dw += __shfl_xor(dw, m); dr += __shfl_xor(dr, m); r2 += __shfl_xor(r2, m);
    }
    if (cg == 0) {
      size_t o = (size_t)b*NN + n;
      ws[OFF_DOTW + o] = dw; ws[OFF_DOTR + o] = dr; ws[OFF_RN2 + o] = r2;
    }
    m0 += v.x; m1 += v.y; m2 += v.z; m3 += v.w;
  }
  atomicAdd(&msum[cg*4+0], m0);
  atomicAdd(&msum[cg*4+1], m1);
  atomicAdd(&msum[cg*4+2], m2);
  atomicAdd(&msum[cg*4+3], m3);
  __syncthreads();
  if (t < 64) atomicAdd(&ws[OFF_MSUM + b*64 + t], msum[t]);
}

// ---------------- erase/add vector ----------------
__global__ __launch_bounds__(128) void ea_kernel(
    const float* __restrict__ Wea, const float* __restrict__ bea, float* __restrict__ ws)
{
  int b = blockIdx.x, t = threadIdx.x;
  __shared__ float cat[128], eaS[128], dS[64];
  if (t < 64) cat[t] = ws[OFF_MSUM + b*64 + t] * (1.0f/NN);
  else        cat[t] = ws[OFF_KW + b*64 + (t-64)];
  __syncthreads();
  float acc = bea[t];
  for (int i = 0; i < 128; ++i) acc += cat[i] * Wea[i*128 + t];
  eaS[t] = acc;
  __syncthreads();
  if (t < 64) {
    float dv = eaS[64+t] - sigm(eaS[t]);
    dS[t] = dv;
    ws[OFF_D + b*64 + t] = dv;
  }
  __syncthreads();
  if (t == 0) {
    float dd = 0.f, dk = 0.f;
    for (int i = 0; i < 64; ++i) { float dv = dS[i]; dd += dv*dv; dk += dv * ws[OFF_KR + b*64 + i]; }
    ws[OFF_BS + b*8 + 2] = dd;
    ws[OFF_BS + b*8 + 3] = dk;
  }
}

// ---------------- addressing (softmax -> interpolate -> shift -> sharpen) ----------------
template<int READ>
__global__ __launch_bounds__(1024) void address_kernel(const float* __restrict__ wprev, float* __restrict__ ws)
{
  int b = blockIdx.x, t = threadIdx.x;
  __shared__ float buf[NN];
  __shared__ float red[16];
  const float* prm = ws + (READ ? OFF_PR : OFF_PW) + b*8;
  float beta = prm[0], g = prm[1], s0 = prm[2], s1 = prm[3], s2 = prm[4], gamma = prm[5], knorm = prm[6];
  float psum = ws[OFF_BS + b*8 + (READ ? 0 : 1)];
  float dd2 = ws[OFF_BS + b*8 + 2], dkr = ws[OFF_BS + b*8 + 3];

  float lmax = -INFINITY;
  #pragma unroll
  for (int i = 0; i < 8; ++i) {
    int n = t + i*1024;
    size_t o = (size_t)b*NN + n;
    float dot, rn2v;
    if (READ) {
      float wwv = ws[OFF_WW + o];
      dot  = ws[OFF_DOTR + o] + wwv * dkr;
      rn2v = fmaxf(ws[OFF_RN2 + o] + 2.f*wwv*ws[OFF_DOTD + o] + wwv*wwv*dd2, 0.f);
    } else {
      dot = ws[OFF_DOTW + o]; rn2v = ws[OFF_RN2 + o];
    }
    float c = dot / fmaxf(sqrtf(rn2v) * knorm, 1e-8f);
    float z = beta * c;
    buf[n] = z;
    lmax = fmaxf(lmax, z);
  }
  float zmax = block_reduce_max(lmax, red);
  float lsum = 0.f;
  #pragma unroll
  for (int i = 0; i < 8; ++i) {
    int n = t + i*1024;
    float e = expf(buf[n] - zmax);
    buf[n] = e;
    lsum += e;
  }
  float esum = block_reduce_sum(lsum, red);
  float inv = 1.f/esum;
  #pragma unroll
  for (int i = 0; i < 8; ++i) {
    int n = t + i*1024;
    float wc = buf[n]*inv;
    float wp = wprev[(size_t)b*NN + n] / psum;
    buf[n] = g*wc + (1.f-g)*wp;
  }
  __syncthreads();
  float l2 = 0.f, lswr = 0.f;
  float wpv[8];
  #pragma unroll
  for (int i = 0; i < 8; ++i) {
    int n = t + i*1024;
    float wsv = s0*buf[(n + NN - 1) & (NN-1)] + s1*buf[n] + s2*buf[(n + 1) & (NN-1)];
    float p = powf(wsv, gamma);
    wpv[i] = p; l2 += p;
    if (READ) lswr += p * ws[OFF_WW + (size_t)b*NN + n];
  }
  float wpsum = block_reduce_sum(l2, red);
  float invp = 1.f/wpsum;
  #pragma unroll
  for (int i = 0; i < 8; ++i) {
    int n = t + i*1024;
    ws[(READ ? OFF_WR : OFF_WW) + (size_t)b*NN + n] = wpv[i]*invp;
  }
  if (READ) {
    float swr = block_reduce_sum(lswr, red) * invp;
    if (t == 0) ws[OFF_BS + b*8 + 4] = swr;
  }
}

// ---------------- bank pass 2: bank·d ----------------
__global__ __launch_bounds__(256) void bank_pass2(const float* __restrict__ bank, float* __restrict__ ws)
{
  int blk = blockIdx.x;
  int b  = blk >> 7;
  int n0 = (blk & 127) << 6;
  int t = threadIdx.x;
  int cg = t & 15, rl = t >> 4;
  __shared__ float dS[64];
  if (t < 64) dS[t] = ws[OFF_D + b*64 + t];
  __syncthreads();
  float4 d4 = *(float4*)&dS[cg*4];
  for (int it = 0; it < 4; ++it) {
    int n = n0 + rl + it*16;
    const float4 v = *(const float4*)&bank[((size_t)b*NN + n)*MM + cg*4];
    float dd = v.x*d4.x + v.y*d4.y + v.z*d4.z + v.w*d4.w;
    for (int m = 1; m < 16; m <<= 1) dd += __shfl_xor(dd, m);
    if (cg == 0) ws[OFF_DOTD + (size_t)b*NN + n] = dd;
  }
}

// ---------------- bank pass 3: out0 = sum_n w_r[n]*bank[n,:] ----------------
__global__ __launch_bounds__(256) void bank_pass3(const float* __restrict__ bank, float* __restrict__ ws)
{
  int blk = blockIdx.x;
  int b  = blk >> 7;
  int n0 = (blk & 127) << 6;
  int t = threadIdx.x;
  int cg = t & 15, rl = t >> 4;
  __shared__ float osum[64];
  if (t < 64) osum[t] = 0.f;
  __syncthreads();
  float a0=0.f, a1=0.f, a2=0.f, a3=0.f;
  for (int it = 0; it < 4; ++it) {
    int n = n0 + rl + it*16;
    float wr = ws[OFF_WR + (size_t)b*NN + n];
    const float4 v = *(const float4*)&bank[((size_t)b*NN + n)*MM + cg*4];
    a0 += wr*v.x; a1 += wr*v.y; a2 += wr*v.z; a3 += wr*v.w;
  }
  atomicAdd(&osum[cg*4+0], a0);
  atomicAdd(&osum[cg*4+1], a1);
  atomicAdd(&osum[cg*4+2], a2);
  atomicAdd(&osum[cg*4+3], a3);
  __syncthreads();
  if (t < 64) atomicAdd(&ws[OFF_OUT0 + b*64 + t], osum[t]);
}

// ---------------- final head ----------------
__global__ __launch_bounds__(512) void final_kernel(
    const float* __restrict__ Wsp, const float* __restrict__ bsp,
    const float* __restrict__ Wo,  const float* __restrict__ bo,
    float* __restrict__ out, float* __restrict__ ws)
{
  int b = blockIdx.x, t = threadIdx.x;
  __shared__ float o[64], seq[512];
  if (t < 64) {
    float swr = ws[OFF_BS + b*8 + 4];
    o[t] = ws[OFF_OUT0 + b*64 + t] + swr * ws[OFF_D + b*64 + t];
  }
  __syncthreads();
  float acc = bsp[t];
  for (int i = 0; i < 64; ++i) acc += o[i] * Wsp[i*HIDC + t];
  seq[t] = lrelu(acc);
  __syncthreads();
  if (t < SEQW) {
    float a = bo[t];
    for (int i = 0; i < 512; ++i) a += seq[i] * Wo[i*SEQW + t];
    out[b*SEQW + t] = sigm(a);
  }
}

extern "C" void kernel_launch(void* const* d_in, const int* in_sizes, int n_in,
                              void* d_out, int out_size, void* d_ws, size_t ws_size,
                              hipStream_t stream) {
  const float* x    = (const float*)d_in[0];
  const float* bank = (const float*)d_in[1];
  const float* wrp  = (const float*)d_in[2];
  const float* wwp  = (const float*)d_in[3];
  const float* W0   = (const float*)d_in[4];
  const float* b0   = (const float*)d_in[5];
  const float* W1   = (const float*)d_in[6];
  const float* b1   = (const float*)d_in[7];
  const float* Wc   = (const float*)d_in[8];
  const float* bc   = (const float*)d_in[9];
  const float* Wr   = (const float*)d_in[10];
  const float* br   = (const float*)d_in[11];
  const float* Ww   = (const float*)d_in[12];
  const float* bw   = (const float*)d_in[13];
  const float* Wea  = (const float*)d_in[14];
  const float* bea  = (const float*)d_in[15];
  const float* Wsp  = (const float*)d_in[16];
  const float* bsp  = (const float*)d_in[17];
  const float* Wo   = (const float*)d_in[18];
  const float* bo   = (const float*)d_in[19];
  float* ws  = (float*)d_ws;
  float* out = (float*)d_out;

  // zero the atomic accumulators (mem_sum, out0) every launch
  hipMemsetAsync(ws + OFF_MSUM, 0, 16384*sizeof(float), stream);

  ctrl_kernel<<<BB, 512, 0, stream>>>(x, W0,b0, W1,b1, Wc,bc, Wr,br, Ww,bw, ws);
  prevsum_kernel<<<BB, 256, 0, stream>>>(wrp, wwp, ws);
  bank_pass1<<<BB*NN/64, 256, 0, stream>>>(bank, ws);
  ea_kernel<<<BB, 128, 0, stream>>>(Wea, bea, ws);
  address_kernel<0><<<BB, 1024, 0, stream>>>(wwp, ws);
  bank_pass2<<<BB*NN/64, 256, 0, stream>>>(bank, ws);
  address_kernel<1><<<BB, 1024, 0, stream>>>(wrp, ws);
  bank_pass3<<<BB*NN/64, 256, 0, stream>>>(bank, ws);
  final_kernel<<<BB, 512, 0, stream>>>(Wsp,bsp, Wo,bo, out, ws);
}

// Round 2
// 398.211 us; speedup vs baseline: 1.0535x; 1.0535x over previous
//
#include <hip/hip_runtime.h>
#include <math.h>

#define NN 8192
#define MM 64
#define BB 128
#define HIDC 512
#define OUTC 256
#define SEQW 63

// ---- workspace layout (float offsets), no accumulators -> nothing needs zeroing ----
#define OFF_KR    0                        // B*64
#define OFF_KW    8192                     // B*64
#define OFF_PR    16384                    // B*8: beta,g,s0,s1,s2,gamma,knorm
#define OFF_PW    17408                    // B*8
#define OFF_BS    18432                    // B*8: [2]=dd2 [3]=dkr [4]=swr
#define OFF_D     19456                    // B*64
#define OFF_PMSUM 27648                    // 16384*64 per-block partial column sums
#define OFF_POUT  (27648 + 1048576)        // 16384*64 per-block partial out sums
#define OFF_DOTW  (27648 + 2*1048576)      // B*N
#define OFF_DOTR  (27648 + 3*1048576)      // B*N
#define OFF_RN2   (27648 + 4*1048576)      // B*N
#define OFF_DOTD  (27648 + 5*1048576)      // B*N
#define OFF_WW    (27648 + 6*1048576)      // B*N
#define OFF_WR    (27648 + 7*1048576)      // B*N
// total ~ 33.7 MB

__device__ __forceinline__ float lrelu(float x){ return x > 0.f ? x : 0.01f*x; }
__device__ __forceinline__ float sigm(float x){ return 1.f/(1.f+expf(-x)); }

__device__ float block_reduce_sum(float v, float* red) {
  for (int m = 32; m >= 1; m >>= 1) v += __shfl_xor(v, m);
  int wid = threadIdx.x >> 6;
  int nw = (blockDim.x + 63) >> 6;
  if ((threadIdx.x & 63) == 0) red[wid] = v;
  __syncthreads();
  if (threadIdx.x == 0) { float s = 0.f; for (int i = 0; i < nw; ++i) s += red[i]; red[0] = s; }
  __syncthreads();
  float r = red[0];
  __syncthreads();
  return r;
}

__device__ float block_reduce_max(float v, float* red) {
  for (int m = 32; m >= 1; m >>= 1) v = fmaxf(v, __shfl_xor(v, m));
  int wid = threadIdx.x >> 6;
  int nw = (blockDim.x + 63) >> 6;
  if ((threadIdx.x & 63) == 0) red[wid] = v;
  __syncthreads();
  if (threadIdx.x == 0) { float s = red[0]; for (int i = 1; i < nw; ++i) s = fmaxf(s, red[i]); red[0] = s; }
  __syncthreads();
  float r = red[0];
  __syncthreads();
  return r;
}

// ---------------- controller MLP (tiny) ----------------
__global__ __launch_bounds__(512) void ctrl_kernel(
    const float* __restrict__ x,
    const float* __restrict__ W0, const float* __restrict__ b0,
    const float* __restrict__ W1, const float* __restrict__ b1,
    const float* __restrict__ Wc, const float* __restrict__ bc,
    const float* __restrict__ Wr, const float* __restrict__ br,
    const float* __restrict__ Ww, const float* __restrict__ bw,
    float* __restrict__ ws)
{
  int b = blockIdx.x, t = threadIdx.x;
  __shared__ float xs[64];
  __shared__ float h0[512];
  __shared__ float h1[512];
  __shared__ float ct[256];
  __shared__ float rr[70], rw[70];
  if (t < 64) xs[t] = x[b*64 + t];
  __syncthreads();
  float acc = b0[t];
  for (int i = 0; i < 64; ++i) acc += xs[i] * W0[i*HIDC + t];
  h0[t] = lrelu(acc);
  __syncthreads();
  acc = b1[t];
  for (int i = 0; i < 512; ++i) acc += h0[i] * W1[i*HIDC + t];
  h1[t] = lrelu(acc);
  __syncthreads();
  if (t < 256) {
    acc = bc[t];
    for (int i = 0; i < 512; ++i) acc += h1[i] * Wc[i*OUTC + t];
    ct[t] = lrelu(acc);
  }
  __syncthreads();
  if (t < 70) {
    float ar = br[t], aw = bw[t];
    for (int i = 0; i < 256; ++i) { float c = ct[i]; ar += c * Wr[i*70 + t]; aw += c * Ww[i*70 + t]; }
    rr[t] = ar; rw[t] = aw;
  }
  __syncthreads();
  if (t < 64) { ws[OFF_KR + b*64 + t] = rr[t]; ws[OFF_KW + b*64 + t] = rw[t]; }
  if (t == 0) {
    float* p = ws + OFF_PR + b*8;
    p[0] = fmaxf(rr[64], 0.f) + 1e-8f;
    p[1] = sigm(rr[65]);
    float m = fmaxf(rr[66], fmaxf(rr[67], rr[68]));
    float e0 = expf(rr[66]-m), e1 = expf(rr[67]-m), e2 = expf(rr[68]-m);
    float ss = e0+e1+e2;
    p[2] = e0/ss; p[3] = e1/ss; p[4] = e2/ss;
    p[5] = fmaxf(rr[69], 0.f) + 1.f;
    float n2 = 0.f; for (int i = 0; i < 64; ++i) n2 += rr[i]*rr[i];
    p[6] = sqrtf(n2);
  }
  if (t == 1) {
    float* p = ws + OFF_PW + b*8;
    p[0] = fmaxf(rw[64], 0.f) + 1e-8f;
    p[1] = sigm(rw[65]);
    float m = fmaxf(rw[66], fmaxf(rw[67], rw[68]));
    float e0 = expf(rw[66]-m), e1 = expf(rw[67]-m), e2 = expf(rw[68]-m);
    float ss = e0+e1+e2;
    p[2] = e0/ss; p[3] = e1/ss; p[4] = e2/ss;
    p[5] = fmaxf(rw[69], 0.f) + 1.f;
    float n2 = 0.f; for (int i = 0; i < 64; ++i) n2 += rw[i]*rw[i];
    p[6] = sqrtf(n2);
  }
}

// ---------------- bank pass 1: partial mem_sum, bank·kw, bank·kr, ||row||^2 ----------------
__global__ __launch_bounds__(256) void bank_pass1(const float* __restrict__ bank, float* __restrict__ ws)
{
  int blk = blockIdx.x;
  int b  = blk >> 7;              // 128 chunks per batch
  int n0 = (blk & 127) << 6;      // 64 rows per block
  int t = threadIdx.x;
  int cg = t & 15;                // 16 lanes per row (4 floats each)
  int rl = t >> 4;                // 0..15
  __shared__ float kwS[64], krS[64], msum[64];
  if (t < 64) { kwS[t] = ws[OFF_KW + b*64 + t]; krS[t] = ws[OFF_KR + b*64 + t]; msum[t] = 0.f; }
  __syncthreads();
  float4 kw4 = *(float4*)&kwS[cg*4];
  float4 kr4 = *(float4*)&krS[cg*4];
  float m0=0.f, m1=0.f, m2=0.f, m3=0.f;
  for (int it = 0; it < 4; ++it) {
    int n = n0 + rl + it*16;
    const float4 v = *(const float4*)&bank[((size_t)b*NN + n)*MM + cg*4];
    float dw = v.x*kw4.x + v.y*kw4.y + v.z*kw4.z + v.w*kw4.w;
    float dr = v.x*kr4.x + v.y*kr4.y + v.z*kr4.z + v.w*kr4.w;
    float r2 = v.x*v.x + v.y*v.y + v.z*v.z + v.w*v.w;
    for (int m = 1; m < 16; m <<= 1) {
      dw += __shfl_xor(dw, m); dr += __shfl_xor(dr, m); r2 += __shfl_xor(r2, m);
    }
    if (cg == 0) {
      size_t o = (size_t)b*NN + n;
      ws[OFF_DOTW + o] = dw; ws[OFF_DOTR + o] = dr; ws[OFF_RN2 + o] = r2;
    }
    m0 += v.x; m1 += v.y; m2 += v.z; m3 += v.w;
  }
  atomicAdd(&msum[cg*4+0], m0);
  atomicAdd(&msum[cg*4+1], m1);
  atomicAdd(&msum[cg*4+2], m2);
  atomicAdd(&msum[cg*4+3], m3);
  __syncthreads();
  if (t < 64) ws[OFF_PMSUM + (size_t)blk*64 + t] = msum[t];   // per-block partial, no atomics
}

// ---------------- addressing; READ=0 carries the ea-prefix (mem_avg reduce + erase/add) ----------------
template<int READ>
__global__ __launch_bounds__(1024) void address_kernel(
    const float* __restrict__ wprev,
    const float* __restrict__ Wea, const float* __restrict__ bea,
    float* __restrict__ ws)
{
  int b = blockIdx.x, t = threadIdx.x;
  __shared__ float buf[NN];
  __shared__ float red[16];
  __shared__ float cat[128], eaS[128], dS[64];

  // phase 0: w_prev values -> regs, block sum (replaces prevsum kernel)
  float wpr[8];
  float lps = 0.f;
  #pragma unroll
  for (int i = 0; i < 8; ++i) {
    wpr[i] = wprev[(size_t)b*NN + t + i*1024];
    lps += wpr[i];
  }
  float psum = block_reduce_sum(lps, red);

  if (!READ) {
    // ea prefix: reduce mem_sum partials, Wea matmul, d = a - e, dd2, dkr
    if (t < 64) {
      float s = 0.f;
      for (int ch = 0; ch < 128; ++ch) s += ws[OFF_PMSUM + ((size_t)b*128 + ch)*64 + t];
      cat[t] = s * (1.0f/NN);
    } else if (t < 128) {
      cat[t] = ws[OFF_KW + b*64 + (t-64)];
    }
    __syncthreads();
    if (t < 128) {
      float acc = bea[t];
      for (int i = 0; i < 128; ++i) acc += cat[i] * Wea[i*128 + t];
      eaS[t] = acc;
    }
    __syncthreads();
    if (t < 64) {
      float dv = eaS[64+t] - sigm(eaS[t]);
      dS[t] = dv;
      ws[OFF_D + b*64 + t] = dv;
    }
    __syncthreads();
    if (t == 0) {
      float dd = 0.f, dk = 0.f;
      for (int i = 0; i < 64; ++i) { float dv = dS[i]; dd += dv*dv; dk += dv * ws[OFF_KR + b*64 + i]; }
      ws[OFF_BS + b*8 + 2] = dd;
      ws[OFF_BS + b*8 + 3] = dk;
    }
    __syncthreads();
  }

  const float* prm = ws + (READ ? OFF_PR : OFF_PW) + b*8;
  float beta = prm[0], g = prm[1], s0 = prm[2], s1 = prm[3], s2 = prm[4], gamma = prm[5], knorm = prm[6];
  float dd2 = 0.f, dkr = 0.f;
  if (READ) { dd2 = ws[OFF_BS + b*8 + 2]; dkr = ws[OFF_BS + b*8 + 3]; }

  float lmax = -INFINITY;
  #pragma unroll
  for (int i = 0; i < 8; ++i) {
    int n = t + i*1024;
    size_t o = (size_t)b*NN + n;
    float dot, rn2v;
    if (READ) {
      float wwv = ws[OFF_WW + o];
      dot  = ws[OFF_DOTR + o] + wwv * dkr;
      rn2v = fmaxf(ws[OFF_RN2 + o] + 2.f*wwv*ws[OFF_DOTD + o] + wwv*wwv*dd2, 0.f);
    } else {
      dot = ws[OFF_DOTW + o]; rn2v = ws[OFF_RN2 + o];
    }
    float c = dot / fmaxf(sqrtf(rn2v) * knorm, 1e-8f);
    float z = beta * c;
    buf[n] = z;
    lmax = fmaxf(lmax, z);
  }
  float zmax = block_reduce_max(lmax, red);
  float lsum = 0.f;
  #pragma unroll
  for (int i = 0; i < 8; ++i) {
    int n = t + i*1024;
    float e = expf(buf[n] - zmax);
    buf[n] = e;
    lsum += e;
  }
  float esum = block_reduce_sum(lsum, red);
  float inv = 1.f/esum;
  float ipsum = 1.f/psum;
  #pragma unroll
  for (int i = 0; i < 8; ++i) {
    int n = t + i*1024;
    float wc = buf[n]*inv;
    buf[n] = g*wc + (1.f-g)*(wpr[i]*ipsum);
  }
  __syncthreads();
  float l2 = 0.f, lswr = 0.f;
  float wpv[8];
  #pragma unroll
  for (int i = 0; i < 8; ++i) {
    int n = t + i*1024;
    float wsv = s0*buf[(n + NN - 1) & (NN-1)] + s1*buf[n] + s2*buf[(n + 1) & (NN-1)];
    float p = powf(wsv, gamma);
    wpv[i] = p; l2 += p;
    if (READ) lswr += p * ws[OFF_WW + (size_t)b*NN + n];
  }
  float wpsum = block_reduce_sum(l2, red);
  float invp = 1.f/wpsum;
  #pragma unroll
  for (int i = 0; i < 8; ++i) {
    int n = t + i*1024;
    ws[(READ ? OFF_WR : OFF_WW) + (size_t)b*NN + n] = wpv[i]*invp;
  }
  if (READ) {
    float swr = block_reduce_sum(lswr, red) * invp;
    if (t == 0) ws[OFF_BS + b*8 + 4] = swr;
  }
}

// ---------------- bank pass 2: bank·d ----------------
__global__ __launch_bounds__(256) void bank_pass2(const float* __restrict__ bank, float* __restrict__ ws)
{
  int blk = blockIdx.x;
  int b  = blk >> 7;
  int n0 = (blk & 127) << 6;
  int t = threadIdx.x;
  int cg = t & 15, rl = t >> 4;
  __shared__ float dS[64];
  if (t < 64) dS[t] = ws[OFF_D + b*64 + t];
  __syncthreads();
  float4 d4 = *(float4*)&dS[cg*4];
  for (int it = 0; it < 4; ++it) {
    int n = n0 + rl + it*16;
    const float4 v = *(const float4*)&bank[((size_t)b*NN + n)*MM + cg*4];
    float dd = v.x*d4.x + v.y*d4.y + v.z*d4.z + v.w*d4.w;
    for (int m = 1; m < 16; m <<= 1) dd += __shfl_xor(dd, m);
    if (cg == 0) ws[OFF_DOTD + (size_t)b*NN + n] = dd;
  }
}

// ---------------- bank pass 3: partial out0 = sum_n w_r[n]*bank[n,:] ----------------
__global__ __launch_bounds__(256) void bank_pass3(const float* __restrict__ bank, float* __restrict__ ws)
{
  int blk = blockIdx.x;
  int b  = blk >> 7;
  int n0 = (blk & 127) << 6;
  int t = threadIdx.x;
  int cg = t & 15, rl = t >> 4;
  __shared__ float osum[64];
  if (t < 64) osum[t] = 0.f;
  __syncthreads();
  float a0=0.f, a1=0.f, a2=0.f, a3=0.f;
  for (int it = 0; it < 4; ++it) {
    int n = n0 + rl + it*16;
    float wr = ws[OFF_WR + (size_t)b*NN + n];
    const float4 v = *(const float4*)&bank[((size_t)b*NN + n)*MM + cg*4];
    a0 += wr*v.x; a1 += wr*v.y; a2 += wr*v.z; a3 += wr*v.w;
  }
  atomicAdd(&osum[cg*4+0], a0);
  atomicAdd(&osum[cg*4+1], a1);
  atomicAdd(&osum[cg*4+2], a2);
  atomicAdd(&osum[cg*4+3], a3);
  __syncthreads();
  if (t < 64) ws[OFF_POUT + (size_t)blk*64 + t] = osum[t];    // per-block partial, no atomics
}

// ---------------- final head (reduces out0 partials) ----------------
__global__ __launch_bounds__(512) void final_kernel(
    const float* __restrict__ Wsp, const float* __restrict__ bsp,
    const float* __restrict__ Wo,  const float* __restrict__ bo,
    float* __restrict__ out, float* __restrict__ ws)
{
  int b = blockIdx.x, t = threadIdx.x;
  __shared__ float o[64], seq[512];
  if (t < 64) {
    float s = 0.f;
    for (int ch = 0; ch < 128; ++ch) s += ws[OFF_POUT + ((size_t)b*128 + ch)*64 + t];
    float swr = ws[OFF_BS + b*8 + 4];
    o[t] = s + swr * ws[OFF_D + b*64 + t];
  }
  __syncthreads();
  float acc = bsp[t];
  for (int i = 0; i < 64; ++i) acc += o[i] * Wsp[i*HIDC + t];
  seq[t] = lrelu(acc);
  __syncthreads();
  if (t < SEQW) {
    float a = bo[t];
    for (int i = 0; i < 512; ++i) a += seq[i] * Wo[i*SEQW + t];
    out[b*SEQW + t] = sigm(a);
  }
}

extern "C" void kernel_launch(void* const* d_in, const int* in_sizes, int n_in,
                              void* d_out, int out_size, void* d_ws, size_t ws_size,
                              hipStream_t stream) {
  const float* x    = (const float*)d_in[0];
  const float* bank = (const float*)d_in[1];
  const float* wrp  = (const float*)d_in[2];
  const float* wwp  = (const float*)d_in[3];
  const float* W0   = (const float*)d_in[4];
  const float* b0   = (const float*)d_in[5];
  const float* W1   = (const float*)d_in[6];
  const float* b1   = (const float*)d_in[7];
  const float* Wc   = (const float*)d_in[8];
  const float* bc   = (const float*)d_in[9];
  const float* Wr   = (const float*)d_in[10];
  const float* br   = (const float*)d_in[11];
  const float* Ww   = (const float*)d_in[12];
  const float* bw   = (const float*)d_in[13];
  const float* Wea  = (const float*)d_in[14];
  const float* bea  = (const float*)d_in[15];
  const float* Wsp  = (const float*)d_in[16];
  const float* bsp  = (const float*)d_in[17];
  const float* Wo   = (const float*)d_in[18];
  const float* bo   = (const float*)d_in[19];
  float* ws  = (float*)d_ws;
  float* out = (float*)d_out;

  ctrl_kernel<<<BB, 512, 0, stream>>>(x, W0,b0, W1,b1, Wc,bc, Wr,br, Ww,bw, ws);
  bank_pass1<<<BB*NN/64, 256, 0, stream>>>(bank, ws);
  address_kernel<0><<<BB, 1024, 0, stream>>>(wwp, Wea, bea, ws);
  bank_pass2<<<BB*NN/64, 256, 0, stream>>>(bank, ws);
  address_kernel<1><<<BB, 1024, 0, stream>>>(wrp, Wea, bea, ws);
  bank_pass3<<<BB*NN/64, 256, 0, stream>>>(bank, ws);
  final_kernel<<<BB, 512, 0, stream>>>(Wsp,bsp, Wo,bo, out, ws);
}

// Round 3
// 296.919 us; speedup vs baseline: 1.4129x; 1.3411x over previous
//
#include <hip/hip_runtime.h>
#include <math.h>

#define NN 8192
#define MM 64
#define BB 128
#define HIDC 512
#define OUTC 256
#define SEQW 63

// 64 blocks per batch for bank passes (128 rows per block)
#define CHUNKS 64

// ---- workspace layout (float offsets), no accumulators -> nothing needs zeroing ----
#define OFF_KR    0                        // B*64
#define OFF_KW    8192                     // B*64
#define OFF_PR    16384                    // B*8: beta,g,s0,s1,s2,gamma,knorm
#define OFF_PW    17408                    // B*8
#define OFF_BS    18432                    // B*8: [2]=dd2 [3]=dkr [4]=swr
#define OFF_D     19456                    // B*64
#define OFF_PMSUM 27648                    // 8192*64 per-block partial column sums
#define OFF_POUT  (27648 + 524288)         // 8192*64 per-block partial out sums
#define OFF_DOTW  (27648 + 2*524288)       // B*N
#define OFF_DOTR  (27648 + 2*524288 + 1048576)    // B*N
#define OFF_RN2   (27648 + 2*524288 + 2*1048576)  // B*N
#define OFF_DOTD  (27648 + 2*524288 + 3*1048576)  // B*N
#define OFF_WW    (27648 + 2*524288 + 4*1048576)  // B*N
#define OFF_WR    (27648 + 2*524288 + 5*1048576)  // B*N

__device__ __forceinline__ float lrelu(float x){ return x > 0.f ? x : 0.01f*x; }
__device__ __forceinline__ float sigm(float x){ return 1.f/(1.f+__expf(-x)); }

__device__ float block_reduce_sum(float v, float* red) {
  for (int m = 32; m >= 1; m >>= 1) v += __shfl_xor(v, m);
  int wid = threadIdx.x >> 6;
  int nw = (blockDim.x + 63) >> 6;
  if ((threadIdx.x & 63) == 0) red[wid] = v;
  __syncthreads();
  if (threadIdx.x == 0) { float s = 0.f; for (int i = 0; i < nw; ++i) s += red[i]; red[0] = s; }
  __syncthreads();
  float r = red[0];
  __syncthreads();
  return r;
}

__device__ float block_reduce_max(float v, float* red) {
  for (int m = 32; m >= 1; m >>= 1) v = fmaxf(v, __shfl_xor(v, m));
  int wid = threadIdx.x >> 6;
  int nw = (blockDim.x + 63) >> 6;
  if ((threadIdx.x & 63) == 0) red[wid] = v;
  __syncthreads();
  if (threadIdx.x == 0) { float s = red[0]; for (int i = 1; i < nw; ++i) s = fmaxf(s, red[i]); red[0] = s; }
  __syncthreads();
  float r = red[0];
  __syncthreads();
  return r;
}

// ---------------- controller MLP (tiny) ----------------
__global__ __launch_bounds__(512) void ctrl_kernel(
    const float* __restrict__ x,
    const float* __restrict__ W0, const float* __restrict__ b0,
    const float* __restrict__ W1, const float* __restrict__ b1,
    const float* __restrict__ Wc, const float* __restrict__ bc,
    const float* __restrict__ Wr, const float* __restrict__ br,
    const float* __restrict__ Ww, const float* __restrict__ bw,
    float* __restrict__ ws)
{
  int b = blockIdx.x, t = threadIdx.x;
  __shared__ float xs[64];
  __shared__ float h0[512];
  __shared__ float h1[512];
  __shared__ float ct[256];
  __shared__ float rr[70], rw[70];
  if (t < 64) xs[t] = x[b*64 + t];
  __syncthreads();
  float acc = b0[t];
  for (int i = 0; i < 64; ++i) acc += xs[i] * W0[i*HIDC + t];
  h0[t] = lrelu(acc);
  __syncthreads();
  acc = b1[t];
  for (int i = 0; i < 512; ++i) acc += h0[i] * W1[i*HIDC + t];
  h1[t] = lrelu(acc);
  __syncthreads();
  if (t < 256) {
    acc = bc[t];
    for (int i = 0; i < 512; ++i) acc += h1[i] * Wc[i*OUTC + t];
    ct[t] = lrelu(acc);
  }
  __syncthreads();
  if (t < 70) {
    float ar = br[t], aw = bw[t];
    for (int i = 0; i < 256; ++i) { float c = ct[i]; ar += c * Wr[i*70 + t]; aw += c * Ww[i*70 + t]; }
    rr[t] = ar; rw[t] = aw;
  }
  __syncthreads();
  if (t < 64) { ws[OFF_KR + b*64 + t] = rr[t]; ws[OFF_KW + b*64 + t] = rw[t]; }
  if (t == 0) {
    float* p = ws + OFF_PR + b*8;
    p[0] = fmaxf(rr[64], 0.f) + 1e-8f;
    p[1] = sigm(rr[65]);
    float m = fmaxf(rr[66], fmaxf(rr[67], rr[68]));
    float e0 = expf(rr[66]-m), e1 = expf(rr[67]-m), e2 = expf(rr[68]-m);
    float ss = e0+e1+e2;
    p[2] = e0/ss; p[3] = e1/ss; p[4] = e2/ss;
    p[5] = fmaxf(rr[69], 0.f) + 1.f;
    float n2 = 0.f; for (int i = 0; i < 64; ++i) n2 += rr[i]*rr[i];
    p[6] = sqrtf(n2);
  }
  if (t == 1) {
    float* p = ws + OFF_PW + b*8;
    p[0] = fmaxf(rw[64], 0.f) + 1e-8f;
    p[1] = sigm(rw[65]);
    float m = fmaxf(rw[66], fmaxf(rw[67], rw[68]));
    float e0 = expf(rw[66]-m), e1 = expf(rw[67]-m), e2 = expf(rw[68]-m);
    float ss = e0+e1+e2;
    p[2] = e0/ss; p[3] = e1/ss; p[4] = e2/ss;
    p[5] = fmaxf(rw[69], 0.f) + 1.f;
    float n2 = 0.f; for (int i = 0; i < 64; ++i) n2 += rw[i]*rw[i];
    p[6] = sqrtf(n2);
  }
}

// ---------------- bank pass 1: all loads up-front, interleaved reduces ----------------
__global__ __launch_bounds__(256, 4) void bank_pass1(const float* __restrict__ bank, float* __restrict__ ws)
{
  int blk = blockIdx.x;
  int b  = blk >> 6;              // 64 chunks per batch
  int n0 = (blk & 63) << 7;       // 128 rows per block
  int t = threadIdx.x;
  int cg = t & 15;                // 16 lanes per row (4 floats each)
  int rl = t >> 4;                // 0..15
  __shared__ float kwS[64], krS[64], msum[64];
  if (t < 64) { kwS[t] = ws[OFF_KW + b*64 + t]; krS[t] = ws[OFF_KR + b*64 + t]; msum[t] = 0.f; }
  __syncthreads();
  float4 kw4 = *(float4*)&kwS[cg*4];
  float4 kr4 = *(float4*)&krS[cg*4];

  float4 v[8];
  #pragma unroll
  for (int it = 0; it < 8; ++it) {
    int n = n0 + rl + it*16;
    v[it] = *(const float4*)&bank[((size_t)b*NN + n)*MM + cg*4];
  }
  float dw[8], dr[8], r2[8];
  float m0=0.f, m1=0.f, m2=0.f, m3=0.f;
  #pragma unroll
  for (int it = 0; it < 8; ++it) {
    dw[it] = v[it].x*kw4.x + v[it].y*kw4.y + v[it].z*kw4.z + v[it].w*kw4.w;
    dr[it] = v[it].x*kr4.x + v[it].y*kr4.y + v[it].z*kr4.z + v[it].w*kr4.w;
    r2[it] = v[it].x*v[it].x + v[it].y*v[it].y + v[it].z*v[it].z + v[it].w*v[it].w;
    m0 += v[it].x; m1 += v[it].y; m2 += v[it].z; m3 += v[it].w;
  }
  #pragma unroll
  for (int m = 1; m < 16; m <<= 1) {
    #pragma unroll
    for (int it = 0; it < 8; ++it) {
      dw[it] += __shfl_xor(dw[it], m);
      dr[it] += __shfl_xor(dr[it], m);
      r2[it] += __shfl_xor(r2[it], m);
    }
  }
  if (cg == 0) {
    size_t base = (size_t)b*NN + n0 + rl;
    #pragma unroll
    for (int it = 0; it < 8; ++it) {
      ws[OFF_DOTW + base + it*16] = dw[it];
      ws[OFF_DOTR + base + it*16] = dr[it];
      ws[OFF_RN2  + base + it*16] = r2[it];
    }
  }
  atomicAdd(&msum[cg*4+0], m0);
  atomicAdd(&msum[cg*4+1], m1);
  atomicAdd(&msum[cg*4+2], m2);
  atomicAdd(&msum[cg*4+3], m3);
  __syncthreads();
  if (t < 64) ws[OFF_PMSUM + (size_t)blk*64 + t] = msum[t];
}

// ---------------- addressing; READ=0 carries the ea-prefix ----------------
template<int READ>
__global__ __launch_bounds__(1024, 4) void address_kernel(
    const float* __restrict__ wprev,
    const float* __restrict__ Wea, const float* __restrict__ bea,
    float* __restrict__ ws)
{
  int b = blockIdx.x, t = threadIdx.x;
  __shared__ float buf[NN];
  __shared__ float red[16];
  __shared__ float cat[128], eaS[128], dS[64];

  float wpr[8];
  float lps = 0.f;
  #pragma unroll
  for (int i = 0; i < 8; ++i) {
    wpr[i] = wprev[(size_t)b*NN + t + i*1024];
    lps += wpr[i];
  }
  float psum = block_reduce_sum(lps, red);

  if (!READ) {
    if (t < 64) {
      float s = 0.f;
      for (int ch = 0; ch < CHUNKS; ++ch) s += ws[OFF_PMSUM + ((size_t)b*CHUNKS + ch)*64 + t];
      cat[t] = s * (1.0f/NN);
    } else if (t < 128) {
      cat[t] = ws[OFF_KW + b*64 + (t-64)];
    }
    __syncthreads();
    if (t < 128) {
      float acc = bea[t];
      for (int i = 0; i < 128; ++i) acc += cat[i] * Wea[i*128 + t];
      eaS[t] = acc;
    }
    __syncthreads();
    if (t < 64) {
      float dv = eaS[64+t] - sigm(eaS[t]);
      dS[t] = dv;
      ws[OFF_D + b*64 + t] = dv;
    }
    __syncthreads();
    if (t == 0) {
      float dd = 0.f, dk = 0.f;
      for (int i = 0; i < 64; ++i) { float dv = dS[i]; dd += dv*dv; dk += dv * ws[OFF_KR + b*64 + i]; }
      ws[OFF_BS + b*8 + 2] = dd;
      ws[OFF_BS + b*8 + 3] = dk;
    }
    __syncthreads();
  }

  const float* prm = ws + (READ ? OFF_PR : OFF_PW) + b*8;
  float beta = prm[0], g = prm[1], s0 = prm[2], s1 = prm[3], s2 = prm[4], gamma = prm[5], knorm = prm[6];
  float dd2 = 0.f, dkr = 0.f;
  if (READ) { dd2 = ws[OFF_BS + b*8 + 2]; dkr = ws[OFF_BS + b*8 + 3]; }

  float lmax = -INFINITY;
  #pragma unroll
  for (int i = 0; i < 8; ++i) {
    int n = t + i*1024;
    size_t o = (size_t)b*NN + n;
    float dot, rn2v;
    if (READ) {
      float wwv = ws[OFF_WW + o];
      dot  = ws[OFF_DOTR + o] + wwv * dkr;
      rn2v = fmaxf(ws[OFF_RN2 + o] + 2.f*wwv*ws[OFF_DOTD + o] + wwv*wwv*dd2, 0.f);
    } else {
      dot = ws[OFF_DOTW + o]; rn2v = ws[OFF_RN2 + o];
    }
    float c = dot / fmaxf(sqrtf(rn2v) * knorm, 1e-8f);
    float z = beta * c;
    buf[n] = z;
    lmax = fmaxf(lmax, z);
  }
  float zmax = block_reduce_max(lmax, red);
  float lsum = 0.f;
  #pragma unroll
  for (int i = 0; i < 8; ++i) {
    int n = t + i*1024;
    float e = __expf(buf[n] - zmax);
    buf[n] = e;
    lsum += e;
  }
  float esum = block_reduce_sum(lsum, red);
  float inv = 1.f/esum;
  float ipsum = 1.f/psum;
  #pragma unroll
  for (int i = 0; i < 8; ++i) {
    int n = t + i*1024;
    float wc = buf[n]*inv;
    buf[n] = g*wc + (1.f-g)*(wpr[i]*ipsum);
  }
  __syncthreads();
  float l2 = 0.f, lswr = 0.f;
  float wpv[8];
  #pragma unroll
  for (int i = 0; i < 8; ++i) {
    int n = t + i*1024;
    float wsv = s0*buf[(n + NN - 1) & (NN-1)] + s1*buf[n] + s2*buf[(n + 1) & (NN-1)];
    float p = exp2f(gamma * log2f(wsv));
    wpv[i] = p; l2 += p;
    if (READ) lswr += p * ws[OFF_WW + (size_t)b*NN + n];
  }
  float wpsum = block_reduce_sum(l2, red);
  float invp = 1.f/wpsum;
  #pragma unroll
  for (int i = 0; i < 8; ++i) {
    int n = t + i*1024;
    ws[(READ ? OFF_WR : OFF_WW) + (size_t)b*NN + n] = wpv[i]*invp;
  }
  if (READ) {
    float swr = block_reduce_sum(lswr, red) * invp;
    if (t == 0) ws[OFF_BS + b*8 + 4] = swr;
  }
}

// ---------------- bank pass 2: bank·d, deep-pipelined ----------------
__global__ __launch_bounds__(256, 4) void bank_pass2(const float* __restrict__ bank, float* __restrict__ ws)
{
  int blk = blockIdx.x;
  int b  = blk >> 6;
  int n0 = (blk & 63) << 7;
  int t = threadIdx.x;
  int cg = t & 15, rl = t >> 4;
  __shared__ float dS[64];
  if (t < 64) dS[t] = ws[OFF_D + b*64 + t];
  __syncthreads();
  float4 d4 = *(float4*)&dS[cg*4];

  float4 v[8];
  #pragma unroll
  for (int it = 0; it < 8; ++it) {
    int n = n0 + rl + it*16;
    v[it] = *(const float4*)&bank[((size_t)b*NN + n)*MM + cg*4];
  }
  float dd[8];
  #pragma unroll
  for (int it = 0; it < 8; ++it)
    dd[it] = v[it].x*d4.x + v[it].y*d4.y + v[it].z*d4.z + v[it].w*d4.w;
  #pragma unroll
  for (int m = 1; m < 16; m <<= 1) {
    #pragma unroll
    for (int it = 0; it < 8; ++it) dd[it] += __shfl_xor(dd[it], m);
  }
  if (cg == 0) {
    size_t base = (size_t)b*NN + n0 + rl;
    #pragma unroll
    for (int it = 0; it < 8; ++it) ws[OFF_DOTD + base + it*16] = dd[it];
  }
}

// ---------------- bank pass 3: partial out0, deep-pipelined, no shuffles ----------------
__global__ __launch_bounds__(256, 4) void bank_pass3(const float* __restrict__ bank, float* __restrict__ ws)
{
  int blk = blockIdx.x;
  int b  = blk >> 6;
  int n0 = (blk & 63) << 7;
  int t = threadIdx.x;
  int cg = t & 15, rl = t >> 4;
  __shared__ float osum[64];
  if (t < 64) osum[t] = 0.f;
  __syncthreads();

  float wrv[8];
  #pragma unroll
  for (int it = 0; it < 8; ++it)
    wrv[it] = ws[OFF_WR + (size_t)b*NN + n0 + rl + it*16];
  float4 v[8];
  #pragma unroll
  for (int it = 0; it < 8; ++it) {
    int n = n0 + rl + it*16;
    v[it] = *(const float4*)&bank[((size_t)b*NN + n)*MM + cg*4];
  }
  float a0=0.f, a1=0.f, a2=0.f, a3=0.f;
  #pragma unroll
  for (int it = 0; it < 8; ++it) {
    a0 += wrv[it]*v[it].x; a1 += wrv[it]*v[it].y;
    a2 += wrv[it]*v[it].z; a3 += wrv[it]*v[it].w;
  }
  atomicAdd(&osum[cg*4+0], a0);
  atomicAdd(&osum[cg*4+1], a1);
  atomicAdd(&osum[cg*4+2], a2);
  atomicAdd(&osum[cg*4+3], a3);
  __syncthreads();
  if (t < 64) ws[OFF_POUT + (size_t)blk*64 + t] = osum[t];
}

// ---------------- final head (reduces out0 partials) ----------------
__global__ __launch_bounds__(512) void final_kernel(
    const float* __restrict__ Wsp, const float* __restrict__ bsp,
    const float* __restrict__ Wo,  const float* __restrict__ bo,
    float* __restrict__ out, float* __restrict__ ws)
{
  int b = blockIdx.x, t = threadIdx.x;
  __shared__ float o[64], seq[512];
  if (t < 64) {
    float s = 0.f;
    for (int ch = 0; ch < CHUNKS; ++ch) s += ws[OFF_POUT + ((size_t)b*CHUNKS + ch)*64 + t];
    float swr = ws[OFF_BS + b*8 + 4];
    o[t] = s + swr * ws[OFF_D + b*64 + t];
  }
  __syncthreads();
  float acc = bsp[t];
  for (int i = 0; i < 64; ++i) acc += o[i] * Wsp[i*HIDC + t];
  seq[t] = lrelu(acc);
  __syncthreads();
  if (t < SEQW) {
    float a = bo[t];
    for (int i = 0; i < 512; ++i) a += seq[i] * Wo[i*SEQW + t];
    out[b*SEQW + t] = sigm(a);
  }
}

extern "C" void kernel_launch(void* const* d_in, const int* in_sizes, int n_in,
                              void* d_out, int out_size, void* d_ws, size_t ws_size,
                              hipStream_t stream) {
  const float* x    = (const float*)d_in[0];
  const float* bank = (const float*)d_in[1];
  const float* wrp  = (const float*)d_in[2];
  const float* wwp  = (const float*)d_in[3];
  const float* W0   = (const float*)d_in[4];
  const float* b0   = (const float*)d_in[5];
  const float* W1   = (const float*)d_in[6];
  const float* b1   = (const float*)d_in[7];
  const float* Wc   = (const float*)d_in[8];
  const float* bc   = (const float*)d_in[9];
  const float* Wr   = (const float*)d_in[10];
  const float* br   = (const float*)d_in[11];
  const float* Ww   = (const float*)d_in[12];
  const float* bw   = (const float*)d_in[13];
  const float* Wea  = (const float*)d_in[14];
  const float* bea  = (const float*)d_in[15];
  const float* Wsp  = (const float*)d_in[16];
  const float* bsp  = (const float*)d_in[17];
  const float* Wo   = (const float*)d_in[18];
  const float* bo   = (const float*)d_in[19];
  float* ws  = (float*)d_ws;
  float* out = (float*)d_out;

  ctrl_kernel<<<BB, 512, 0, stream>>>(x, W0,b0, W1,b1, Wc,bc, Wr,br, Ww,bw, ws);
  bank_pass1<<<BB*CHUNKS, 256, 0, stream>>>(bank, ws);
  address_kernel<0><<<BB, 1024, 0, stream>>>(wwp, Wea, bea, ws);
  bank_pass2<<<BB*CHUNKS, 256, 0, stream>>>(bank, ws);
  address_kernel<1><<<BB, 1024, 0, stream>>>(wrp, Wea, bea, ws);
  bank_pass3<<<BB*CHUNKS, 256, 0, stream>>>(bank, ws);
  final_kernel<<<BB, 512, 0, stream>>>(Wsp,bsp, Wo,bo, out, ws);
}

// Round 4
// 265.694 us; speedup vs baseline: 1.5790x; 1.1175x over previous
//
#include <hip/hip_runtime.h>
#include <math.h>

#define NN 8192
#define MM 64
#define BB 128
#define HIDC 512
#define OUTC 256
#define SEQW 63

__device__ __forceinline__ float lrelu(float x){ return x > 0.f ? x : 0.01f*x; }
__device__ __forceinline__ float sigm(float x){ return 1.f/(1.f+__expf(-x)); }

// block-wide reductions for 1024 threads (16 waves)
__device__ float block_reduce_sum(float v, float* red) {
  for (int m = 32; m >= 1; m >>= 1) v += __shfl_xor(v, m);
  int wid = threadIdx.x >> 6;
  if ((threadIdx.x & 63) == 0) red[wid] = v;
  __syncthreads();
  if (threadIdx.x == 0) { float s = 0.f; for (int i = 0; i < 16; ++i) s += red[i]; red[0] = s; }
  __syncthreads();
  float r = red[0];
  __syncthreads();
  return r;
}

__device__ float block_reduce_max(float v, float* red) {
  for (int m = 32; m >= 1; m >>= 1) v = fmaxf(v, __shfl_xor(v, m));
  int wid = threadIdx.x >> 6;
  if ((threadIdx.x & 63) == 0) red[wid] = v;
  __syncthreads();
  if (threadIdx.x == 0) { float s = red[0]; for (int i = 1; i < 16; ++i) s = fmaxf(s, red[i]); red[0] = s; }
  __syncthreads();
  float r = red[0];
  __syncthreads();
  return r;
}

// One workgroup == one batch. All phases fused; N-sized intermediates in LDS.
__global__ __launch_bounds__(1024, 1) void ntm_fused(
    const float* __restrict__ x,    const float* __restrict__ bank,
    const float* __restrict__ wrp,  const float* __restrict__ wwp,
    const float* __restrict__ W0,   const float* __restrict__ b0,
    const float* __restrict__ W1,   const float* __restrict__ b1,
    const float* __restrict__ Wc,   const float* __restrict__ bc,
    const float* __restrict__ Wr,   const float* __restrict__ br,
    const float* __restrict__ Ww,   const float* __restrict__ bw,
    const float* __restrict__ Wea,  const float* __restrict__ bea,
    const float* __restrict__ Wsp,  const float* __restrict__ bsp,
    const float* __restrict__ Wo,   const float* __restrict__ bo,
    float* __restrict__ out)
{
  const int b = blockIdx.x;
  const int t = threadIdx.x;

  // big LDS arrays (4 x 32 KB)
  __shared__ float A[NN];   // dotw -> z-buf(addr0) -> wr(addr1 output)
  __shared__ float Bb[NN];  // dotr -> adj_dot(pass2) -> z-buf(addr1, in-place)
  __shared__ float C[NN];   // rn2  -> adj_rn2(pass2)
  __shared__ float E[NN];   // ww
  // scratch
  __shared__ float red[16];
  __shared__ float msum[64];     // mem column sums / out0 partial
  __shared__ float dvec[64];     // d = a - e
  __shared__ float prm[20];      // [0..7]=write params, [8..15]=read params, 16=dd2,17=dkr,18=swr
  __shared__ float cat[128], eaS[128];
  __shared__ float h0[HIDC], h1[HIDC], ct[OUTC], rrr[72], rww[72];

  const int cg = t & 15;          // 16 lanes per row, 4 floats each
  const int rl = t >> 4;          // 0..63 row-in-sweep
  const float* bbase = bank + (size_t)b * NN * MM;

  // ---------------- phase 0: controller MLP ----------------
  if (t < 64) cat[t] = x[b*64 + t];
  __syncthreads();
  if (t < HIDC) {
    float acc = b0[t];
    #pragma unroll 4
    for (int i = 0; i < 64; ++i) acc += cat[i] * W0[i*HIDC + t];
    h0[t] = lrelu(acc);
  }
  __syncthreads();
  if (t < HIDC) {
    float acc = b1[t];
    for (int i = 0; i < HIDC; ++i) acc += h0[i] * W1[i*HIDC + t];
    h1[t] = lrelu(acc);
  }
  __syncthreads();
  if (t < OUTC) {
    float acc = bc[t];
    for (int i = 0; i < HIDC; ++i) acc += h1[i] * Wc[i*OUTC + t];
    ct[t] = lrelu(acc);
  }
  __syncthreads();
  if (t < 70) {
    float ar = br[t], aw = bw[t];
    for (int i = 0; i < OUTC; ++i) { float c = ct[i]; ar += c * Wr[i*70 + t]; aw += c * Ww[i*70 + t]; }
    rrr[t] = ar; rww[t] = aw;
  }
  __syncthreads();
  if (t < 2) {
    const float* rv = (t == 0) ? rww : rrr;     // t=0: write set, t=1: read set
    float* p = prm + t*8;
    p[0] = fmaxf(rv[64], 0.f) + 1e-8f;          // beta
    p[1] = 1.f/(1.f+expf(-rv[65]));             // g
    float m = fmaxf(rv[66], fmaxf(rv[67], rv[68]));
    float e0 = expf(rv[66]-m), e1 = expf(rv[67]-m), e2 = expf(rv[68]-m);
    float ss = e0+e1+e2;
    p[2] = e0/ss; p[3] = e1/ss; p[4] = e2/ss;   // shift softmax
    p[5] = fmaxf(rv[69], 0.f) + 1.f;            // gamma
    float n2 = 0.f;
    for (int i = 0; i < 64; ++i) n2 += rv[i]*rv[i];
    p[6] = sqrtf(n2);                           // |k|
  }
  if (t < 64) msum[t] = 0.f;
  __syncthreads();

  // ---------------- pass 1: dotw->A, dotr->Bb, rn2->C, column sums->msum ----------------
  {
    float4 kw4 = *(float4*)&rww[cg*4];
    float4 kr4 = *(float4*)&rrr[cg*4];
    float m0=0.f, m1=0.f, m2=0.f, m3=0.f;
    for (int sup = 0; sup < 16; ++sup) {
      float4 v[8];
      #pragma unroll
      for (int j = 0; j < 8; ++j) {
        int n = (sup*8 + j)*64 + rl;
        v[j] = *(const float4*)&bbase[(size_t)n*MM + cg*4];
      }
      float dw[8], dr[8], r2[8];
      #pragma unroll
      for (int j = 0; j < 8; ++j) {
        dw[j] = v[j].x*kw4.x + v[j].y*kw4.y + v[j].z*kw4.z + v[j].w*kw4.w;
        dr[j] = v[j].x*kr4.x + v[j].y*kr4.y + v[j].z*kr4.z + v[j].w*kr4.w;
        r2[j] = v[j].x*v[j].x + v[j].y*v[j].y + v[j].z*v[j].z + v[j].w*v[j].w;
        m0 += v[j].x; m1 += v[j].y; m2 += v[j].z; m3 += v[j].w;
      }
      #pragma unroll
      for (int m = 1; m < 16; m <<= 1) {
        #pragma unroll
        for (int j = 0; j < 8; ++j) {
          dw[j] += __shfl_xor(dw[j], m);
          dr[j] += __shfl_xor(dr[j], m);
          r2[j] += __shfl_xor(r2[j], m);
        }
      }
      if (cg == 0) {
        #pragma unroll
        for (int j = 0; j < 8; ++j) {
          int n = (sup*8 + j)*64 + rl;
          A[n] = dw[j]; Bb[n] = dr[j]; C[n] = r2[j];
        }
      }
    }
    atomicAdd(&msum[cg*4+0], m0);
    atomicAdd(&msum[cg*4+1], m1);
    atomicAdd(&msum[cg*4+2], m2);
    atomicAdd(&msum[cg*4+3], m3);
  }
  __syncthreads();

  // ---------------- ea: d = a - sigmoid(e_pre), dd2, dkr ----------------
  if (t < 64)      cat[t] = msum[t] * (1.0f/NN);
  else if (t < 128) cat[t] = rww[t-64];
  __syncthreads();
  if (t < 128) {
    float acc = bea[t];
    for (int i = 0; i < 128; ++i) acc += cat[i] * Wea[i*128 + t];
    eaS[t] = acc;
  }
  __syncthreads();
  if (t < 64) dvec[t] = eaS[64+t] - sigm(eaS[t]);
  __syncthreads();
  if (t == 0) {
    float dd = 0.f, dk = 0.f;
    for (int i = 0; i < 64; ++i) { float dv = dvec[i]; dd += dv*dv; dk += dv*rrr[i]; }
    prm[16] = dd; prm[17] = dk;
  }
  __syncthreads();

  // ---------------- addr0 (write addressing): dot=A, rn2=C, out ww->E ----------------
  {
    float wpr[8]; float lps = 0.f;
    #pragma unroll
    for (int i = 0; i < 8; ++i) { wpr[i] = wwp[(size_t)b*NN + t + i*1024]; lps += wpr[i]; }
    float psum = block_reduce_sum(lps, red);
    float beta = prm[0], g = prm[1], s0 = prm[2], s1 = prm[3], s2 = prm[4], gamma = prm[5], knorm = prm[6];
    float lmax = -INFINITY;
    #pragma unroll
    for (int i = 0; i < 8; ++i) {
      int n = t + i*1024;
      float c = A[n] / fmaxf(sqrtf(C[n]) * knorm, 1e-8f);
      float z = beta * c;
      A[n] = z;
      lmax = fmaxf(lmax, z);
    }
    float zmax = block_reduce_max(lmax, red);
    float lsum = 0.f;
    #pragma unroll
    for (int i = 0; i < 8; ++i) {
      int n = t + i*1024;
      float e = __expf(A[n] - zmax);
      A[n] = e; lsum += e;
    }
    float esum = block_reduce_sum(lsum, red);
    float inv = 1.f/esum, ipsum = 1.f/psum;
    #pragma unroll
    for (int i = 0; i < 8; ++i) {
      int n = t + i*1024;
      A[n] = g*A[n]*inv + (1.f-g)*(wpr[i]*ipsum);
    }
    __syncthreads();
    float l2 = 0.f;
    float wpv[8];
    #pragma unroll
    for (int i = 0; i < 8; ++i) {
      int n = t + i*1024;
      float wsv = s0*A[(n + NN - 1) & (NN-1)] + s1*A[n] + s2*A[(n + 1) & (NN-1)];
      float p = exp2f(gamma * log2f(wsv));
      wpv[i] = p; l2 += p;
    }
    float wpsum = block_reduce_sum(l2, red);
    float invp = 1.f/wpsum;
    #pragma unroll
    for (int i = 0; i < 8; ++i) E[t + i*1024] = wpv[i]*invp;
  }
  __syncthreads();

  // ---------------- pass 2: dotd; fold into Bb (adj dot) and C (adj rn2) ----------------
  {
    float4 d4 = *(float4*)&dvec[cg*4];
    float dd2 = prm[16], dkr = prm[17];
    for (int sup = 0; sup < 16; ++sup) {
      float4 v[8];
      #pragma unroll
      for (int j = 0; j < 8; ++j) {
        int n = (sup*8 + j)*64 + rl;
        v[j] = *(const float4*)&bbase[(size_t)n*MM + cg*4];
      }
      float dd[8];
      #pragma unroll
      for (int j = 0; j < 8; ++j)
        dd[j] = v[j].x*d4.x + v[j].y*d4.y + v[j].z*d4.z + v[j].w*d4.w;
      #pragma unroll
      for (int m = 1; m < 16; m <<= 1) {
        #pragma unroll
        for (int j = 0; j < 8; ++j) dd[j] += __shfl_xor(dd[j], m);
      }
      if (cg == 0) {
        #pragma unroll
        for (int j = 0; j < 8; ++j) {
          int n = (sup*8 + j)*64 + rl;
          float wwv = E[n];
          Bb[n] += wwv * dkr;
          C[n]  = fmaxf(C[n] + 2.f*wwv*dd[j] + wwv*wwv*dd2, 0.f);
        }
      }
    }
  }
  __syncthreads();

  // ---------------- addr1 (read addressing): dot=Bb, rn2=C, out wr->A, swr ----------------
  {
    float wpr[8]; float lps = 0.f;
    #pragma unroll
    for (int i = 0; i < 8; ++i) { wpr[i] = wrp[(size_t)b*NN + t + i*1024]; lps += wpr[i]; }
    float psum = block_reduce_sum(lps, red);
    float beta = prm[8], g = prm[9], s0 = prm[10], s1 = prm[11], s2 = prm[12], gamma = prm[13], knorm = prm[14];
    float lmax = -INFINITY;
    #pragma unroll
    for (int i = 0; i < 8; ++i) {
      int n = t + i*1024;
      float c = Bb[n] / fmaxf(sqrtf(C[n]) * knorm, 1e-8f);
      float z = beta * c;
      Bb[n] = z;
      lmax = fmaxf(lmax, z);
    }
    float zmax = block_reduce_max(lmax, red);
    float lsum = 0.f;
    #pragma unroll
    for (int i = 0; i < 8; ++i) {
      int n = t + i*1024;
      float e = __expf(Bb[n] - zmax);
      Bb[n] = e; lsum += e;
    }
    float esum = block_reduce_sum(lsum, red);
    float inv = 1.f/esum, ipsum = 1.f/psum;
    #pragma unroll
    for (int i = 0; i < 8; ++i) {
      int n = t + i*1024;
      Bb[n] = g*Bb[n]*inv + (1.f-g)*(wpr[i]*ipsum);
    }
    __syncthreads();
    float l2 = 0.f, lswr = 0.f;
    float wpv[8];
    #pragma unroll
    for (int i = 0; i < 8; ++i) {
      int n = t + i*1024;
      float wsv = s0*Bb[(n + NN - 1) & (NN-1)] + s1*Bb[n] + s2*Bb[(n + 1) & (NN-1)];
      float p = exp2f(gamma * log2f(wsv));
      wpv[i] = p; l2 += p;
      lswr += p * E[n];
    }
    float wpsum = block_reduce_sum(l2, red);
    float invp = 1.f/wpsum;
    #pragma unroll
    for (int i = 0; i < 8; ++i) A[t + i*1024] = wpv[i]*invp;
    float swr = block_reduce_sum(lswr, red) * invp;
    if (t == 0) prm[18] = swr;
  }
  if (t < 64) msum[t] = 0.f;
  __syncthreads();

  // ---------------- pass 3: out0 = sum_n wr[n]*bank[n,:] ----------------
  {
    float a0=0.f, a1=0.f, a2=0.f, a3=0.f;
    for (int sup = 0; sup < 16; ++sup) {
      float4 v[8];
      float wrv[8];
      #pragma unroll
      for (int j = 0; j < 8; ++j) {
        int n = (sup*8 + j)*64 + rl;
        v[j] = *(const float4*)&bbase[(size_t)n*MM + cg*4];
        wrv[j] = A[n];
      }
      #pragma unroll
      for (int j = 0; j < 8; ++j) {
        a0 += wrv[j]*v[j].x; a1 += wrv[j]*v[j].y;
        a2 += wrv[j]*v[j].z; a3 += wrv[j]*v[j].w;
      }
    }
    atomicAdd(&msum[cg*4+0], a0);
    atomicAdd(&msum[cg*4+1], a1);
    atomicAdd(&msum[cg*4+2], a2);
    atomicAdd(&msum[cg*4+3], a3);
  }
  __syncthreads();

  // ---------------- final head ----------------
  if (t < 64) cat[t] = msum[t] + prm[18] * dvec[t];   // o = out0 + swr*d
  __syncthreads();
  if (t < HIDC) {
    float acc = bsp[t];
    #pragma unroll 4
    for (int i = 0; i < 64; ++i) acc += cat[i] * Wsp[i*HIDC + t];
    h0[t] = lrelu(acc);
  }
  __syncthreads();
  if (t < SEQW) {
    float a = bo[t];
    for (int i = 0; i < HIDC; ++i) a += h0[i] * Wo[i*SEQW + t];
    out[b*SEQW + t] = sigm(a);
  }
}

extern "C" void kernel_launch(void* const* d_in, const int* in_sizes, int n_in,
                              void* d_out, int out_size, void* d_ws, size_t ws_size,
                              hipStream_t stream) {
  const float* x    = (const float*)d_in[0];
  const float* bank = (const float*)d_in[1];
  const float* wrp  = (const float*)d_in[2];
  const float* wwp  = (const float*)d_in[3];
  const float* W0   = (const float*)d_in[4];
  const float* b0   = (const float*)d_in[5];
  const float* W1   = (const float*)d_in[6];
  const float* b1   = (const float*)d_in[7];
  const float* Wc   = (const float*)d_in[8];
  const float* bc   = (const float*)d_in[9];
  const float* Wr   = (const float*)d_in[10];
  const float* br   = (const float*)d_in[11];
  const float* Ww   = (const float*)d_in[12];
  const float* bw   = (const float*)d_in[13];
  const float* Wea  = (const float*)d_in[14];
  const float* bea  = (const float*)d_in[15];
  const float* Wsp  = (const float*)d_in[16];
  const float* bsp  = (const float*)d_in[17];
  const float* Wo   = (const float*)d_in[18];
  const float* bo   = (const float*)d_in[19];
  float* out = (float*)d_out;

  ntm_fused<<<BB, 1024, 0, stream>>>(x, bank, wrp, wwp,
                                     W0,b0, W1,b1, Wc,bc, Wr,br, Ww,bw,
                                     Wea,bea, Wsp,bsp, Wo,bo, out);
}